// Round 4
// baseline (524.368 us; speedup 1.0000x reference)
//
#include <hip/hip_runtime.h>

#define NN 100000
#define NE 3200000
#define NG 2048
#define FIN 4
#define HD 64
#define NBUK 196          // ceil(100000 / 512) buckets of 512 node ids
#define NB 1024           // histogram blocks
#define CHUNK 3125        // NE / NB exactly
#define SBLK 256
#define NPB 64            // dst nodes per block in gather2 (4 waves x 16)

// ---------------- pass 1: per-block bucket histogram ----------------

__global__ void hist_k(const int* __restrict__ dst, int* __restrict__ counts) {
    __shared__ int h[NBUK];
    for (int i = threadIdx.x; i < NBUK; i += blockDim.x) h[i] = 0;
    __syncthreads();
    int base = blockIdx.x * CHUNK;
    for (int i = threadIdx.x; i < CHUNK; i += blockDim.x)
        atomicAdd(&h[dst[base + i] >> 9], 1);
    __syncthreads();
    for (int k = threadIdx.x; k < NBUK; k += blockDim.x)
        counts[k * NB + blockIdx.x] = h[k];
}

// ---------------- flat exclusive scan of counts (n = NBUK*NB) ----------------

__global__ void scan1_k(const int* __restrict__ in, int* __restrict__ bsum, int n) {
    __shared__ int s[SBLK];
    int i = blockIdx.x * SBLK + threadIdx.x;
    s[threadIdx.x] = (i < n) ? in[i] : 0;
    __syncthreads();
    for (int o = SBLK / 2; o > 0; o >>= 1) {
        if (threadIdx.x < o) s[threadIdx.x] += s[threadIdx.x + o];
        __syncthreads();
    }
    if (threadIdx.x == 0) bsum[blockIdx.x] = s[0];
}

__global__ void scan2_k(int* __restrict__ bsum, int nb) {
    __shared__ int s[1024];
    int t = threadIdx.x;
    int v = (t < nb) ? bsum[t] : 0;
    s[t] = v;
    __syncthreads();
    for (int o = 1; o < 1024; o <<= 1) {
        int u = (t >= o) ? s[t - o] : 0;
        __syncthreads();
        if (t >= o) s[t] += u;
        __syncthreads();
    }
    if (t < nb) bsum[t] = s[t] - v;   // exclusive block prefix
}

__global__ void scan3_k(const int* __restrict__ in, const int* __restrict__ bpre,
                        int* __restrict__ out, int n) {
    __shared__ int s[SBLK];
    int i = blockIdx.x * SBLK + threadIdx.x;
    int v = (i < n) ? in[i] : 0;
    s[threadIdx.x] = v;
    __syncthreads();
    for (int o = 1; o < SBLK; o <<= 1) {
        int u = (threadIdx.x >= o) ? s[threadIdx.x - o] : 0;
        __syncthreads();
        if (threadIdx.x >= o) s[threadIdx.x] += u;
        __syncthreads();
    }
    if (i < n) out[i] = s[threadIdx.x] - v + bpre[blockIdx.x];
}

// ---------------- pass 2: scatter into block-exclusive staging ranges ----------------
// staged value packs (dst & 511) << 17 | src   (src < 2^17)

__global__ void stage_k(const int* __restrict__ src, const int* __restrict__ dst,
                        const int* __restrict__ offs, unsigned int* __restrict__ staging) {
    __shared__ int cur[NBUK];
    for (int k = threadIdx.x; k < NBUK; k += blockDim.x)
        cur[k] = offs[k * NB + blockIdx.x];
    __syncthreads();
    int base = blockIdx.x * CHUNK;
    for (int i = threadIdx.x; i < CHUNK; i += blockDim.x) {
        int d = dst[base + i];
        int s = src[base + i];
        int pos = atomicAdd(&cur[d >> 9], 1);
        staging[pos] = ((unsigned int)(d & 511) << 17) | (unsigned int)s;
    }
}

// ---------------- pass 3: per-bucket fine sort -> CSR, row_ptr, dinv, xs ----------------

__global__ void csr_fill_bucket_k(const unsigned int* __restrict__ staging,
                                  const int* __restrict__ offs,
                                  const float4* __restrict__ x,
                                  int* __restrict__ csr_src, int* __restrict__ row_ptr,
                                  float* __restrict__ dinv, float4* __restrict__ xs) {
    __shared__ int degl[512];
    __shared__ int sc[512];
    __shared__ int cur[512];
    int k = blockIdx.x;
    int t = threadIdx.x;
    int nodeBase = k << 9;
    int s0 = offs[k * NB];
    int s1 = (k < NBUK - 1) ? offs[(k + 1) * NB] : NE;
    degl[t] = 0;
    __syncthreads();
    for (int i = s0 + t; i < s1; i += 512)
        atomicAdd(&degl[staging[i] >> 17], 1);
    __syncthreads();
    int v = degl[t];
    sc[t] = v;
    __syncthreads();
    for (int o = 1; o < 512; o <<= 1) {
        int u = (t >= o) ? sc[t - o] : 0;
        __syncthreads();
        if (t >= o) sc[t] += u;
        __syncthreads();
    }
    int excl = sc[t] - v;
    int node = nodeBase + t;
    if (node < NN) {
        row_ptr[node] = s0 + excl;
        float di = rsqrtf((float)v + 1.0f);
        dinv[node] = di;
        float4 xv = x[node];
        xs[node] = make_float4(xv.x * di, xv.y * di, xv.z * di, xv.w * di);
    }
    cur[t] = s0 + excl;
    if (k == NBUK - 1 && t == 0) row_ptr[NN] = NE;
    __syncthreads();
    for (int i = s0 + t; i < s1; i += 512) {
        unsigned int pv = staging[i];
        int pos = atomicAdd(&cur[pv >> 17], 1);
        csr_src[pos] = (int)(pv & 0x1FFFFu);
    }
}

// ---------------- layer 1: aggregate raw 4-feature x (L2-resident) ----------------
// a1[d] = dinv[d] * ( sum_{s in N(d)} xs[s] + xs[d] ),  xs = dinv * x

__global__ void gather1_k(const float4* __restrict__ xs, const int* __restrict__ csr_src,
                          const int* __restrict__ row_ptr, const float* __restrict__ dinv,
                          float4* __restrict__ a1) {
    int n = blockIdx.x * blockDim.x + threadIdx.x;
    if (n >= NN) return;
    int beg = row_ptr[n], end = row_ptr[n + 1];
    float4 s = xs[n];   // self term
    for (int e = beg; e < end; ++e) {
        float4 w = xs[csr_src[e]];
        s.x += w.x; s.y += w.y; s.z += w.z; s.w += w.w;
    }
    float di = dinv[n];
    a1[n] = make_float4(s.x * di, s.y * di, s.z * di, s.w * di);
}

// h1s (chunked layout) = dinv[node] * relu(a1 @ W1 + b1)
// layout: h1c[(h>>3)*(NN*8) + node*8 + (h&7)]
__global__ void g1mm_k(const float4* __restrict__ a1, const float* __restrict__ W1,
                       const float* __restrict__ b1, const float* __restrict__ dinv,
                       float* __restrict__ h1c) {
    int t = blockIdx.x * blockDim.x + threadIdx.x;
    if (t >= NN * HD) return;
    int node = t >> 6, h = t & 63;
    float4 a = a1[node];
    float v = a.x * W1[h] + a.y * W1[64 + h] + a.z * W1[128 + h] + a.w * W1[192 + h] + b1[h];
    v = fmaxf(v, 0.f) * dinv[node];
    h1c[(h >> 3) * (NN * 8) + node * 8 + (h & 7)] = v;
}

// ---------------- layer 2 gather: XCD-chunked over 8 feature chunks ----------------
// chunk = blockIdx.x % 8 -> one chunk per XCD (3.2 MB, L2-resident)
// a2[d][c*8+f] = sum_{s in N(d)} h1c[c][s][f] + h1c[c][d][f]   (dinv applied later)

__global__ void gather2_k(const float* __restrict__ h1c, const int* __restrict__ csr_src,
                          const int* __restrict__ row_ptr, float* __restrict__ a2) {
    int c = blockIdx.x & 7;
    int nb = blockIdx.x >> 3;
    const float* xc = h1c + (size_t)c * (NN * 8);
    int wave = threadIdx.x >> 6, lane = threadIdx.x & 63;
    int eg = lane >> 3, f = lane & 7;     // edge-group 0..7, feature 0..7
    int node0 = nb * NPB + wave * (NPB / 4);
    for (int r = 0; r < NPB / 4; ++r) {
        int d = node0 + r;
        if (d >= NN) return;
        int beg = row_ptr[d], end = row_ptr[d + 1];
        float acc = 0.f;
        for (int e = beg + eg; e < end; e += 8)
            acc += xc[csr_src[e] * 8 + f];
        acc += __shfl_xor(acc, 8);
        acc += __shfl_xor(acc, 16);
        acc += __shfl_xor(acc, 32);
        if (eg == 0) {
            acc += xc[d * 8 + f];               // self term
            a2[d * 64 + c * 8 + f] = acc;
        }
    }
}

// ---------------- combine2 + pool: out2 = relu(dinv*a2 @ W2 + b2), pool by graph ----------------
// block: 256 threads = 4 waves; covers 16 nodes (wave w -> nodes base+w*4..+3, h = lane)

__global__ void combine2_pool_k(const float* __restrict__ a2, const float* __restrict__ W2,
                                const float* __restrict__ b2, const float* __restrict__ dinv,
                                const int* __restrict__ batch, float* __restrict__ pool) {
    __shared__ float w2s[HD * HD];       // 16 KB
    __shared__ float as2[16][HD];        // staged a2 rows
    __shared__ float vals[16][HD];       // post-relu values
    __shared__ int   bt[16];
    int tid = threadIdx.x;
    int wave = tid >> 6, lane = tid & 63;
    int base = blockIdx.x * 16;
    for (int i = tid; i < HD * HD; i += 256) w2s[i] = W2[i];
    for (int i = tid; i < 16 * HD; i += 256) as2[i >> 6][i & 63] = a2[base * 64 + i];
    if (tid < 16) bt[tid] = batch[base + tid];
    __syncthreads();
#pragma unroll
    for (int i = 0; i < 4; ++i) {
        int nl = wave * 4 + i;           // local node 0..15
        float s = 0.f;
#pragma unroll
        for (int k = 0; k < HD; ++k) s = fmaf(as2[nl][k], w2s[k * HD + lane], s);
        float v = fmaxf(fmaf(dinv[base + nl], s, b2[lane]), 0.f);
        vals[nl][lane] = v;
    }
    __syncthreads();
    if (wave == 0) {   // batch-sorted flush: few atomics per block
        int g = bt[0];
        float acc = 0.f;
        for (int i = 0; i < 16; ++i) {
            int bg = bt[i];
            if (bg != g) { atomicAdd(&pool[g * HD + lane], acc); acc = 0.f; g = bg; }
            acc += vals[i][lane];
        }
        atomicAdd(&pool[g * HD + lane], acc);
    }
}

__global__ void cnt_k(const int* __restrict__ batch, float* __restrict__ pcnt, int n) {
    int t = blockIdx.x * blockDim.x + threadIdx.x;
    if (t < n) atomicAdd(&pcnt[batch[t]], 1.0f);
}

__global__ void final_k(const float* __restrict__ pool, const float* __restrict__ pcnt,
                        const float* __restrict__ Wlin, const float* __restrict__ blin,
                        float* __restrict__ out) {
    int g = blockIdx.x;
    int lane = threadIdx.x;
    float v = pool[g * HD + lane] * Wlin[lane];
#pragma unroll
    for (int off = 32; off > 0; off >>= 1) v += __shfl_down(v, off);
    if (lane == 0) out[g] = v / fmaxf(pcnt[g], 1.0f) + blin[0];
}

// ---------------- launch ----------------

extern "C" void kernel_launch(void* const* d_in, const int* in_sizes, int n_in,
                              void* d_out, int out_size, void* d_ws, size_t ws_size,
                              hipStream_t stream) {
    const float* x    = (const float*)d_in[0];
    const int*   ei   = (const int*)d_in[1];
    const int*   bat  = (const int*)d_in[2];
    const float* W1   = (const float*)d_in[3];
    const float* b1   = (const float*)d_in[4];
    const float* W2   = (const float*)d_in[5];
    const float* b2   = (const float*)d_in[6];
    const float* Wlin = (const float*)d_in[7];
    const float* blin = (const float*)d_in[8];
    float* out = (float*)d_out;

    const int* src = ei;
    const int* dst = ei + NE;

    char* ws = (char*)d_ws;
    size_t off = 0;
    auto alloc = [&](size_t bytes) {
        char* p = ws + off;
        off += (bytes + 255) & ~(size_t)255;
        return p;
    };
    const int NCNT = NBUK * NB;                       // 200704
    int*   counts  = (int*)  alloc(NCNT * sizeof(int));
    int*   offs    = (int*)  alloc(NCNT * sizeof(int));
    int*   bsum    = (int*)  alloc(1024 * sizeof(int));
    int*   row_ptr = (int*)  alloc((NN + 1) * sizeof(int));
    float* dinv    = (float*)alloc(NN * sizeof(float));
    int*   csr_src = (int*)  alloc((size_t)NE * sizeof(int));
    float4* xs     = (float4*)alloc((size_t)NN * sizeof(float4));
    float4* a1     = (float4*)alloc((size_t)NN * sizeof(float4));
    float* h1c     = (float*)alloc((size_t)NN * HD * sizeof(float)); // chunked h1s
    float* a2      = (float*)alloc((size_t)NN * HD * sizeof(float));
    float* pool    = (float*)alloc((size_t)NG * HD * sizeof(float));
    float* pcnt    = (float*)alloc((size_t)NG * sizeof(float));
    // staging aliases a2 (a2 written long after csr build done)
    unsigned int* staging = (unsigned int*)a2;
    (void)ws_size; (void)n_in; (void)in_sizes; (void)out_size;

    const int BLK = 256;
    const int nScanBlocks = (NCNT + SBLK - 1) / SBLK;   // 784
    const int gN  = (NN + BLK - 1) / BLK;
    const int gNH = (int)(((long long)NN * HD + BLK - 1) / BLK);
    const int blocksPerChunk = (NN + NPB - 1) / NPB;    // 1563

    // CSR build (no global atomics, block-exclusive write regions)
    hist_k<<<NB, BLK, 0, stream>>>(dst, counts);
    scan1_k<<<nScanBlocks, SBLK, 0, stream>>>(counts, bsum, NCNT);
    scan2_k<<<1, 1024, 0, stream>>>(bsum, nScanBlocks);
    scan3_k<<<nScanBlocks, SBLK, 0, stream>>>(counts, bsum, offs, NCNT);
    stage_k<<<NB, BLK, 0, stream>>>(src, dst, offs, staging);
    csr_fill_bucket_k<<<NBUK, 512, 0, stream>>>(staging, offs, (const float4*)x,
                                                csr_src, row_ptr, dinv, xs);

    // layer 1: aggregate raw x then tiny GEMM
    gather1_k<<<gN, BLK, 0, stream>>>(xs, csr_src, row_ptr, dinv, a1);
    g1mm_k<<<gNH, BLK, 0, stream>>>(a1, W1, b1, dinv, h1c);

    // layer 2: XCD-chunked aggregate, then GEMM+relu+pool
    gather2_k<<<blocksPerChunk * 8, BLK, 0, stream>>>(h1c, csr_src, row_ptr, a2);
    hipMemsetAsync(pool, 0, (size_t)NG * HD * sizeof(float), stream);
    hipMemsetAsync(pcnt, 0, (size_t)NG * sizeof(float), stream);
    combine2_pool_k<<<NN / 16, BLK, 0, stream>>>(a2, W2, b2, dinv, bat, pool);

    // readout
    cnt_k<<<gN, BLK, 0, stream>>>(bat, pcnt, NN);
    final_k<<<NG, 64, 0, stream>>>(pool, pcnt, Wlin, blin, out);
}

// Round 5
// 315.711 us; speedup vs baseline: 1.6609x; 1.6609x over previous
//
#include <hip/hip_runtime.h>

#define NN 100000
#define NE 3200000
#define NG 2048
#define FIN 4
#define HD 64
#define BUKSZ 256         // nodes per bucket
#define NBUK 391          // ceil(NN / BUKSZ)
#define NB 512            // histogram/stage blocks
#define CHUNK 6250        // NE / NB exactly
#define SBLK 256

// ---------------- pass 1: per-block bucket histogram ----------------

__global__ void hist_k(const int* __restrict__ dst, int* __restrict__ counts) {
    __shared__ int h[NBUK];
    for (int i = threadIdx.x; i < NBUK; i += blockDim.x) h[i] = 0;
    __syncthreads();
    int base = blockIdx.x * CHUNK;
    for (int i = threadIdx.x; i < CHUNK; i += blockDim.x)
        atomicAdd(&h[dst[base + i] >> 8], 1);
    __syncthreads();
    for (int k = threadIdx.x; k < NBUK; k += blockDim.x)
        counts[k * NB + blockIdx.x] = h[k];
}

// ---------------- flat exclusive scan of counts (n = NBUK*NB = 200192) ----------------

__global__ void scan1_k(const int* __restrict__ in, int* __restrict__ bsum, int n) {
    __shared__ int s[SBLK];
    int i = blockIdx.x * SBLK + threadIdx.x;
    s[threadIdx.x] = (i < n) ? in[i] : 0;
    __syncthreads();
    for (int o = SBLK / 2; o > 0; o >>= 1) {
        if (threadIdx.x < o) s[threadIdx.x] += s[threadIdx.x + o];
        __syncthreads();
    }
    if (threadIdx.x == 0) bsum[blockIdx.x] = s[0];
}

__global__ void scan2_k(int* __restrict__ bsum, int nb) {
    __shared__ int s[1024];
    int t = threadIdx.x;
    int v = (t < nb) ? bsum[t] : 0;
    s[t] = v;
    __syncthreads();
    for (int o = 1; o < 1024; o <<= 1) {
        int u = (t >= o) ? s[t - o] : 0;
        __syncthreads();
        if (t >= o) s[t] += u;
        __syncthreads();
    }
    if (t < nb) bsum[t] = s[t] - v;   // exclusive block prefix
}

__global__ void scan3_k(const int* __restrict__ in, const int* __restrict__ bpre,
                        int* __restrict__ out, int n) {
    __shared__ int s[SBLK];
    int i = blockIdx.x * SBLK + threadIdx.x;
    int v = (i < n) ? in[i] : 0;
    s[threadIdx.x] = v;
    __syncthreads();
    for (int o = 1; o < SBLK; o <<= 1) {
        int u = (threadIdx.x >= o) ? s[threadIdx.x - o] : 0;
        __syncthreads();
        if (threadIdx.x >= o) s[threadIdx.x] += u;
        __syncthreads();
    }
    if (i < n) out[i] = s[threadIdx.x] - v + bpre[blockIdx.x];
}

// ---------------- pass 2: scatter into block-exclusive staging ranges ----------------
// staged value packs (dst & 255) << 17 | src   (src < 2^17)

__global__ void stage_k(const int* __restrict__ src, const int* __restrict__ dst,
                        const int* __restrict__ offs, unsigned int* __restrict__ staging) {
    __shared__ int cur[NBUK];
    for (int k = threadIdx.x; k < NBUK; k += blockDim.x)
        cur[k] = offs[k * NB + blockIdx.x];
    __syncthreads();
    int base = blockIdx.x * CHUNK;
    for (int i = threadIdx.x; i < CHUNK; i += blockDim.x) {
        int d = dst[base + i];
        int s = src[base + i];
        int pos = atomicAdd(&cur[d >> 8], 1);
        staging[pos] = ((unsigned int)(d & 255) << 17) | (unsigned int)s;
    }
}

// ---------------- pass 3: per-bucket fine sort -> CSR, row_ptr, dinv, xs ----------------

__global__ void csr_fill_bucket_k(const unsigned int* __restrict__ staging,
                                  const int* __restrict__ offs,
                                  const float4* __restrict__ x,
                                  int* __restrict__ csr_src, int* __restrict__ row_ptr,
                                  float* __restrict__ dinv, float4* __restrict__ xs) {
    __shared__ int degl[BUKSZ];
    __shared__ int sc[BUKSZ];
    __shared__ int cur[BUKSZ];
    int k = blockIdx.x;
    int t = threadIdx.x;
    int nodeBase = k * BUKSZ;
    int s0 = offs[k * NB];
    int s1 = (k < NBUK - 1) ? offs[(k + 1) * NB] : NE;
    degl[t] = 0;
    __syncthreads();
    for (int i = s0 + t; i < s1; i += BUKSZ)
        atomicAdd(&degl[staging[i] >> 17], 1);
    __syncthreads();
    int v = degl[t];
    sc[t] = v;
    __syncthreads();
    for (int o = 1; o < BUKSZ; o <<= 1) {
        int u = (t >= o) ? sc[t - o] : 0;
        __syncthreads();
        if (t >= o) sc[t] += u;
        __syncthreads();
    }
    int excl = sc[t] - v;
    int node = nodeBase + t;
    if (node < NN) {
        row_ptr[node] = s0 + excl;
        float di = rsqrtf((float)v + 1.0f);
        dinv[node] = di;
        float4 xv = x[node];
        xs[node] = make_float4(xv.x * di, xv.y * di, xv.z * di, xv.w * di);
    }
    cur[t] = s0 + excl;
    if (k == NBUK - 1 && t == 0) row_ptr[NN] = NE;
    __syncthreads();
    for (int i = s0 + t; i < s1; i += BUKSZ) {
        unsigned int pv = staging[i];
        int pos = atomicAdd(&cur[pv >> 17], 1);
        csr_src[pos] = (int)(pv & 0x1FFFFu);
    }
}

// ---------------- layer 1: aggregate raw 4-feature x (L2-resident) ----------------
// a1[d] = dinv[d] * ( sum_{s in N(d)} xs[s] + xs[d] ),  xs = dinv * x

__global__ void gather1_k(const float4* __restrict__ xs, const int* __restrict__ csr_src,
                          const int* __restrict__ row_ptr, const float* __restrict__ dinv,
                          float4* __restrict__ a1) {
    int n = blockIdx.x * blockDim.x + threadIdx.x;
    if (n >= NN) return;
    int beg = row_ptr[n], end = row_ptr[n + 1];
    float4 s = xs[n];   // self term
    for (int e = beg; e < end; ++e) {
        float4 w = xs[csr_src[e]];
        s.x += w.x; s.y += w.y; s.z += w.z; s.w += w.w;
    }
    float di = dinv[n];
    a1[n] = make_float4(s.x * di, s.y * di, s.z * di, s.w * di);
}

// h1[node][h] = dinv[node] * relu(a1 @ W1 + b1)   (pre-scaled for layer-2 aggregation)
__global__ void g1mm_k(const float4* __restrict__ a1, const float* __restrict__ W1,
                       const float* __restrict__ b1, const float* __restrict__ dinv,
                       float* __restrict__ h1) {
    int t = blockIdx.x * blockDim.x + threadIdx.x;
    if (t >= NN * HD) return;
    int node = t >> 6, h = t & 63;
    float4 a = a1[node];
    float v = a.x * W1[h] + a.y * W1[64 + h] + a.z * W1[128 + h] + a.w * W1[192 + h] + b1[h];
    v = fmaxf(v, 0.f) * dinv[node];
    h1[t] = v;
}

// ---------------- layer 2 gather: wave per dst node, lane = feature ----------------
// a2[d][h] = sum_{s in N(d)} h1[s][h] + h1[d][h]   (dinv applied in combine2)

__global__ void gather2_k(const float* __restrict__ h1, const int* __restrict__ csr_src,
                          const int* __restrict__ row_ptr, float* __restrict__ a2) {
    int wid = (blockIdx.x * blockDim.x + threadIdx.x) >> 6;
    int lane = threadIdx.x & 63;
    if (wid >= NN) return;
    int beg = row_ptr[wid], end = row_ptr[wid + 1];
    float acc = h1[(size_t)wid * HD + lane];   // self term
    int e = beg;
    for (; e + 8 <= end; e += 8) {
        int s0 = csr_src[e],     s1 = csr_src[e + 1], s2 = csr_src[e + 2], s3 = csr_src[e + 3];
        int s4 = csr_src[e + 4], s5 = csr_src[e + 5], s6 = csr_src[e + 6], s7 = csr_src[e + 7];
        float a0 = h1[(size_t)s0 * HD + lane];
        float a1v = h1[(size_t)s1 * HD + lane];
        float a2v = h1[(size_t)s2 * HD + lane];
        float a3 = h1[(size_t)s3 * HD + lane];
        float a4 = h1[(size_t)s4 * HD + lane];
        float a5 = h1[(size_t)s5 * HD + lane];
        float a6 = h1[(size_t)s6 * HD + lane];
        float a7 = h1[(size_t)s7 * HD + lane];
        acc += ((a0 + a1v) + (a2v + a3)) + ((a4 + a5) + (a6 + a7));
    }
    for (; e < end; ++e) acc += h1[(size_t)csr_src[e] * HD + lane];
    a2[(size_t)wid * HD + lane] = acc;
}

// ---------------- combine2 + pool: h2 = relu(dinv*a2 @ W2 + b2), pool by graph ----------------
// block: 256 threads = 4 waves; covers 16 nodes

__global__ void combine2_pool_k(const float* __restrict__ a2, const float* __restrict__ W2,
                                const float* __restrict__ b2, const float* __restrict__ dinv,
                                const int* __restrict__ batch, float* __restrict__ pool) {
    __shared__ float w2s[HD * HD];       // 16 KB
    __shared__ float as2[16][HD];
    __shared__ float vals[16][HD];
    __shared__ int   bt[16];
    int tid = threadIdx.x;
    int wave = tid >> 6, lane = tid & 63;
    int base = blockIdx.x * 16;
    for (int i = tid; i < HD * HD; i += 256) w2s[i] = W2[i];
    for (int i = tid; i < 16 * HD; i += 256) as2[i >> 6][i & 63] = a2[(size_t)base * HD + i];
    if (tid < 16) bt[tid] = batch[base + tid];
    __syncthreads();
#pragma unroll
    for (int i = 0; i < 4; ++i) {
        int nl = wave * 4 + i;
        float s = 0.f;
#pragma unroll
        for (int k = 0; k < HD; ++k) s = fmaf(as2[nl][k], w2s[k * HD + lane], s);
        float v = fmaxf(fmaf(dinv[base + nl], s, b2[lane]), 0.f);
        vals[nl][lane] = v;
    }
    __syncthreads();
    if (wave == 0) {   // batch-sorted flush: few atomics per block
        int g = bt[0];
        float acc = 0.f;
        for (int i = 0; i < 16; ++i) {
            int bg = bt[i];
            if (bg != g) { atomicAdd(&pool[g * HD + lane], acc); acc = 0.f; g = bg; }
            acc += vals[i][lane];
        }
        atomicAdd(&pool[g * HD + lane], acc);
    }
}

__global__ void cnt_k(const int* __restrict__ batch, float* __restrict__ pcnt, int n) {
    int t = blockIdx.x * blockDim.x + threadIdx.x;
    if (t < n) atomicAdd(&pcnt[batch[t]], 1.0f);
}

__global__ void final_k(const float* __restrict__ pool, const float* __restrict__ pcnt,
                        const float* __restrict__ Wlin, const float* __restrict__ blin,
                        float* __restrict__ out) {
    int g = blockIdx.x;
    int lane = threadIdx.x;
    float v = pool[g * HD + lane] * Wlin[lane];
#pragma unroll
    for (int off = 32; off > 0; off >>= 1) v += __shfl_down(v, off);
    if (lane == 0) out[g] = v / fmaxf(pcnt[g], 1.0f) + blin[0];
}

// ---------------- launch ----------------

extern "C" void kernel_launch(void* const* d_in, const int* in_sizes, int n_in,
                              void* d_out, int out_size, void* d_ws, size_t ws_size,
                              hipStream_t stream) {
    const float* x    = (const float*)d_in[0];
    const int*   ei   = (const int*)d_in[1];
    const int*   bat  = (const int*)d_in[2];
    const float* W1   = (const float*)d_in[3];
    const float* b1   = (const float*)d_in[4];
    const float* W2   = (const float*)d_in[5];
    const float* b2   = (const float*)d_in[6];
    const float* Wlin = (const float*)d_in[7];
    const float* blin = (const float*)d_in[8];
    float* out = (float*)d_out;

    const int* src = ei;
    const int* dst = ei + NE;

    char* ws = (char*)d_ws;
    size_t off = 0;
    auto alloc = [&](size_t bytes) {
        char* p = ws + off;
        off += (bytes + 255) & ~(size_t)255;
        return p;
    };
    const int NCNT = NBUK * NB;                       // 200192
    int*   counts  = (int*)  alloc(NCNT * sizeof(int));
    int*   offs    = (int*)  alloc(NCNT * sizeof(int));
    int*   bsum    = (int*)  alloc(1024 * sizeof(int));
    int*   row_ptr = (int*)  alloc((NN + 1) * sizeof(int));
    float* dinv    = (float*)alloc(NN * sizeof(float));
    int*   csr_src = (int*)  alloc((size_t)NE * sizeof(int));
    float4* xs     = (float4*)alloc((size_t)NN * sizeof(float4));
    float4* a1     = (float4*)alloc((size_t)NN * sizeof(float4));
    float* h1      = (float*)alloc((size_t)NN * HD * sizeof(float));
    float* a2      = (float*)alloc((size_t)NN * HD * sizeof(float));
    float* pool    = (float*)alloc((size_t)NG * HD * sizeof(float));
    float* pcnt    = (float*)alloc((size_t)NG * sizeof(float));
    // staging aliases a2 (a2 written only after csr build consumed staging)
    unsigned int* staging = (unsigned int*)a2;
    (void)ws_size; (void)n_in; (void)in_sizes; (void)out_size;

    const int BLK = 256;
    const int nScanBlocks = (NCNT + SBLK - 1) / SBLK;   // 782
    const int gN  = (NN + BLK - 1) / BLK;
    const int gNH = (int)(((long long)NN * HD + BLK - 1) / BLK);
    const int gW  = (NN * 64 + BLK - 1) / BLK;          // one wave per node

    // CSR build (no global atomics, block-exclusive write regions)
    hist_k<<<NB, BLK, 0, stream>>>(dst, counts);
    scan1_k<<<nScanBlocks, SBLK, 0, stream>>>(counts, bsum, NCNT);
    scan2_k<<<1, 1024, 0, stream>>>(bsum, nScanBlocks);
    scan3_k<<<nScanBlocks, SBLK, 0, stream>>>(counts, bsum, offs, NCNT);
    stage_k<<<NB, BLK, 0, stream>>>(src, dst, offs, staging);
    csr_fill_bucket_k<<<NBUK, BUKSZ, 0, stream>>>(staging, offs, (const float4*)x,
                                                  csr_src, row_ptr, dinv, xs);

    // layer 1: aggregate raw x then tiny GEMM
    gather1_k<<<gN, BLK, 0, stream>>>(xs, csr_src, row_ptr, dinv, a1);
    g1mm_k<<<gNH, BLK, 0, stream>>>(a1, W1, b1, dinv, h1);

    // layer 2: full-width gather then GEMM+relu+pool
    gather2_k<<<gW, BLK, 0, stream>>>(h1, csr_src, row_ptr, a2);
    hipMemsetAsync(pool, 0, (size_t)NG * HD * sizeof(float), stream);
    hipMemsetAsync(pcnt, 0, (size_t)NG * sizeof(float), stream);
    combine2_pool_k<<<NN / 16, BLK, 0, stream>>>(a2, W2, b2, dinv, bat, pool);

    // readout
    cnt_k<<<gN, BLK, 0, stream>>>(bat, pcnt, NN);
    final_k<<<NG, 64, 0, stream>>>(pool, pcnt, Wlin, blin, out);
}

// Round 6
// 258.112 us; speedup vs baseline: 2.0316x; 1.2232x over previous
//
#include <hip/hip_runtime.h>
#include <hip/hip_fp16.h>

#define NN 100000
#define NE 3200000
#define NG 2048
#define FIN 4
#define HD 64
#define BUKSZ 256         // nodes per bucket
#define NBUK 391          // ceil(NN / BUKSZ)
#define NB 512            // histogram/stage blocks
#define CHUNK 6250        // NE / NB exactly
#define SBLK 256

// ---------------- pass 1: per-block bucket histogram ----------------

__global__ void hist_k(const int* __restrict__ dst, int* __restrict__ counts) {
    __shared__ int h[NBUK];
    for (int i = threadIdx.x; i < NBUK; i += blockDim.x) h[i] = 0;
    __syncthreads();
    int base = blockIdx.x * CHUNK;
    for (int i = threadIdx.x; i < CHUNK; i += blockDim.x)
        atomicAdd(&h[dst[base + i] >> 8], 1);
    __syncthreads();
    for (int k = threadIdx.x; k < NBUK; k += blockDim.x)
        counts[k * NB + blockIdx.x] = h[k];
}

// ---------------- flat exclusive scan of counts (n = NBUK*NB = 200192) ----------------

__global__ void scan1_k(const int* __restrict__ in, int* __restrict__ bsum, int n) {
    __shared__ int s[SBLK];
    int i = blockIdx.x * SBLK + threadIdx.x;
    s[threadIdx.x] = (i < n) ? in[i] : 0;
    __syncthreads();
    for (int o = SBLK / 2; o > 0; o >>= 1) {
        if (threadIdx.x < o) s[threadIdx.x] += s[threadIdx.x + o];
        __syncthreads();
    }
    if (threadIdx.x == 0) bsum[blockIdx.x] = s[0];
}

__global__ void scan2_k(int* __restrict__ bsum, int nb) {
    __shared__ int s[1024];
    int t = threadIdx.x;
    int v = (t < nb) ? bsum[t] : 0;
    s[t] = v;
    __syncthreads();
    for (int o = 1; o < 1024; o <<= 1) {
        int u = (t >= o) ? s[t - o] : 0;
        __syncthreads();
        if (t >= o) s[t] += u;
        __syncthreads();
    }
    if (t < nb) bsum[t] = s[t] - v;   // exclusive block prefix
}

__global__ void scan3_k(const int* __restrict__ in, const int* __restrict__ bpre,
                        int* __restrict__ out, int n) {
    __shared__ int s[SBLK];
    int i = blockIdx.x * SBLK + threadIdx.x;
    int v = (i < n) ? in[i] : 0;
    s[threadIdx.x] = v;
    __syncthreads();
    for (int o = 1; o < SBLK; o <<= 1) {
        int u = (threadIdx.x >= o) ? s[threadIdx.x - o] : 0;
        __syncthreads();
        if (threadIdx.x >= o) s[threadIdx.x] += u;
        __syncthreads();
    }
    if (i < n) out[i] = s[threadIdx.x] - v + bpre[blockIdx.x];
}

// ---------------- pass 2: scatter into block-exclusive staging ranges ----------------
// staged value packs (dst & 255) << 17 | src   (src < 2^17)

__global__ void stage_k(const int* __restrict__ src, const int* __restrict__ dst,
                        const int* __restrict__ offs, unsigned int* __restrict__ staging) {
    __shared__ int cur[NBUK];
    for (int k = threadIdx.x; k < NBUK; k += blockDim.x)
        cur[k] = offs[k * NB + blockIdx.x];
    __syncthreads();
    int base = blockIdx.x * CHUNK;
    for (int i = threadIdx.x; i < CHUNK; i += blockDim.x) {
        int d = dst[base + i];
        int s = src[base + i];
        int pos = atomicAdd(&cur[d >> 8], 1);
        staging[pos] = ((unsigned int)(d & 255) << 17) | (unsigned int)s;
    }
}

// ---------------- pass 3: per-bucket fine sort -> CSR, row_ptr, dinv, xs ----------------
// 512 threads per bucket of 256 nodes

__global__ void csr_fill_bucket_k(const unsigned int* __restrict__ staging,
                                  const int* __restrict__ offs,
                                  const float4* __restrict__ x,
                                  int* __restrict__ csr_src, int* __restrict__ row_ptr,
                                  float* __restrict__ dinv, float4* __restrict__ xs) {
    __shared__ int degl[BUKSZ];
    __shared__ int sc[BUKSZ];
    __shared__ int cur[BUKSZ];
    int k = blockIdx.x;
    int t = threadIdx.x;
    int nodeBase = k * BUKSZ;
    int s0 = offs[k * NB];
    int s1 = (k < NBUK - 1) ? offs[(k + 1) * NB] : NE;
    if (t < BUKSZ) degl[t] = 0;
    __syncthreads();
    for (int i = s0 + t; i < s1; i += 512)
        atomicAdd(&degl[staging[i] >> 17], 1);
    __syncthreads();
    int v = 0;
    if (t < BUKSZ) { v = degl[t]; sc[t] = v; }
    __syncthreads();
    for (int o = 1; o < BUKSZ; o <<= 1) {
        int u = 0;
        if (t < BUKSZ && t >= o) u = sc[t - o];
        __syncthreads();
        if (t < BUKSZ && t >= o) sc[t] += u;
        __syncthreads();
    }
    if (t < BUKSZ) {
        int excl = sc[t] - v;
        int node = nodeBase + t;
        if (node < NN) {
            row_ptr[node] = s0 + excl;
            float di = rsqrtf((float)v + 1.0f);
            dinv[node] = di;
            float4 xv = x[node];
            xs[node] = make_float4(xv.x * di, xv.y * di, xv.z * di, xv.w * di);
        }
        cur[t] = s0 + excl;
        if (k == NBUK - 1 && t == 0) row_ptr[NN] = NE;
    }
    __syncthreads();
    for (int i = s0 + t; i < s1; i += 512) {
        unsigned int pv = staging[i];
        int pos = atomicAdd(&cur[pv >> 17], 1);
        csr_src[pos] = (int)(pv & 0x1FFFFu);
    }
}

// ---------------- layer 1: aggregate raw 4-feature x, 16 lanes per node ----------------
// a1[d] = dinv[d] * ( sum_{s in N(d)} xs[s] + xs[d] ),  xs = dinv * x

__global__ void gather1_k(const float4* __restrict__ xs, const int* __restrict__ csr_src,
                          const int* __restrict__ row_ptr, const float* __restrict__ dinv,
                          float4* __restrict__ a1) {
    int tid = blockIdx.x * blockDim.x + threadIdx.x;
    int node = tid >> 4;
    int sub = tid & 15;
    if (node >= NN) return;
    int beg = row_ptr[node], end = row_ptr[node + 1];
    float4 s = make_float4(0.f, 0.f, 0.f, 0.f);
    for (int e = beg + sub; e < end; e += 16) {
        float4 w = xs[csr_src[e]];
        s.x += w.x; s.y += w.y; s.z += w.z; s.w += w.w;
    }
#pragma unroll
    for (int o = 1; o < 16; o <<= 1) {
        s.x += __shfl_xor(s.x, o);
        s.y += __shfl_xor(s.y, o);
        s.z += __shfl_xor(s.z, o);
        s.w += __shfl_xor(s.w, o);
    }
    if (sub == 0) {
        float4 self = xs[node];
        float di = dinv[node];
        a1[node] = make_float4((s.x + self.x) * di, (s.y + self.y) * di,
                               (s.z + self.z) * di, (s.w + self.w) * di);
    }
}

// h1[node][2j..2j+1] = fp16( dinv[node] * relu(a1 @ W1 + b1) )  -- half2 stores
__global__ void g1mm_k(const float4* __restrict__ a1, const float* __restrict__ W1,
                       const float* __restrict__ b1, const float* __restrict__ dinv,
                       __half2* __restrict__ h1) {
    int t = blockIdx.x * blockDim.x + threadIdx.x;
    if (t >= NN * 32) return;
    int node = t >> 5, j = (t & 31) << 1;       // features j, j+1
    float4 a = a1[node];
    float di = dinv[node];
    float v0 = a.x * W1[j] + a.y * W1[64 + j] + a.z * W1[128 + j] + a.w * W1[192 + j] + b1[j];
    float v1 = a.x * W1[j + 1] + a.y * W1[64 + j + 1] + a.z * W1[128 + j + 1] + a.w * W1[192 + j + 1] + b1[j + 1];
    v0 = fmaxf(v0, 0.f) * di;
    v1 = fmaxf(v1, 0.f) * di;
    h1[t] = __floats2half2_rn(v0, v1);
}

// ---------------- layer 2 gather: wave = 1 dst node, 2 edges/iter (half-wave each) ----------------
// a2[d][h] = sum_{s in N(d)} h1[s][h] + h1[d][h]   (fp16 source, fp32 accum)

__global__ void gather2_k(const __half* __restrict__ h1, const int* __restrict__ csr_src,
                          const int* __restrict__ row_ptr, float* __restrict__ a2) {
    int wid = (blockIdx.x * blockDim.x + threadIdx.x) >> 6;
    int lane = threadIdx.x & 63;
    if (wid >= NN) return;
    int half = lane >> 5, f2 = lane & 31;
    int beg = row_ptr[wid], end = row_ptr[wid + 1];
    float ax = 0.f, ay = 0.f;
    int e = beg + half;
    for (; e + 2 < end; e += 4) {               // 2 edges per half per iter
        int s0 = csr_src[e];
        int s1 = csr_src[e + 2];
        __half2 h0 = ((const __half2*)(h1 + (size_t)s0 * HD))[f2];
        __half2 h2 = ((const __half2*)(h1 + (size_t)s1 * HD))[f2];
        float2 f0 = __half22float2(h0);
        float2 f1 = __half22float2(h2);
        ax += f0.x + f1.x;
        ay += f0.y + f1.y;
    }
    for (; e < end; e += 2) {
        int s0 = csr_src[e];
        float2 f0 = __half22float2(((const __half2*)(h1 + (size_t)s0 * HD))[f2]);
        ax += f0.x; ay += f0.y;
    }
    ax += __shfl_xor(ax, 32);
    ay += __shfl_xor(ay, 32);
    float2 self = __half22float2(((const __half2*)(h1 + (size_t)wid * HD))[f2]);
    ax += self.x; ay += self.y;
    if (half == 0)
        ((float2*)(a2 + (size_t)wid * HD))[f2] = make_float2(ax, ay);
}

// ---------------- combine2 + pool: h2 = relu(dinv*a2 @ W2 + b2), pool by graph ----------------

__global__ void combine2_pool_k(const float* __restrict__ a2, const float* __restrict__ W2,
                                const float* __restrict__ b2, const float* __restrict__ dinv,
                                const int* __restrict__ batch, float* __restrict__ pool) {
    __shared__ float w2s[HD * HD];       // 16 KB
    __shared__ float as2[16][HD];
    __shared__ float vals[16][HD];
    __shared__ int   bt[16];
    int tid = threadIdx.x;
    int wave = tid >> 6, lane = tid & 63;
    int base = blockIdx.x * 16;
    for (int i = tid; i < HD * HD; i += 256) w2s[i] = W2[i];
    for (int i = tid; i < 16 * HD; i += 256) as2[i >> 6][i & 63] = a2[(size_t)base * HD + i];
    if (tid < 16) bt[tid] = batch[base + tid];
    __syncthreads();
#pragma unroll
    for (int i = 0; i < 4; ++i) {
        int nl = wave * 4 + i;
        float s = 0.f;
#pragma unroll
        for (int k = 0; k < HD; ++k) s = fmaf(as2[nl][k], w2s[k * HD + lane], s);
        float v = fmaxf(fmaf(dinv[base + nl], s, b2[lane]), 0.f);
        vals[nl][lane] = v;
    }
    __syncthreads();
    if (wave == 0) {   // batch-sorted flush: few atomics per block
        int g = bt[0];
        float acc = 0.f;
        for (int i = 0; i < 16; ++i) {
            int bg = bt[i];
            if (bg != g) { atomicAdd(&pool[g * HD + lane], acc); acc = 0.f; g = bg; }
            acc += vals[i][lane];
        }
        atomicAdd(&pool[g * HD + lane], acc);
    }
}

// one wave per graph; node count via binary search in sorted batch
__device__ __forceinline__ int lb_dev(const int* __restrict__ b, int n, int key) {
    int lo = 0, hi = n;
    while (lo < hi) {
        int mid = (lo + hi) >> 1;
        if (b[mid] < key) lo = mid + 1; else hi = mid;
    }
    return lo;
}

__global__ void final_k(const float* __restrict__ pool, const int* __restrict__ batch,
                        const float* __restrict__ Wlin, const float* __restrict__ blin,
                        float* __restrict__ out) {
    int g = blockIdx.x;
    int lane = threadIdx.x;
    int lo = lb_dev(batch, NN, g);
    int hi = lb_dev(batch, NN, g + 1);
    float cnt = (float)(hi - lo);
    float v = pool[g * HD + lane] * Wlin[lane];
#pragma unroll
    for (int off = 32; off > 0; off >>= 1) v += __shfl_down(v, off);
    if (lane == 0) out[g] = v / fmaxf(cnt, 1.0f) + blin[0];
}

// ---------------- launch ----------------

extern "C" void kernel_launch(void* const* d_in, const int* in_sizes, int n_in,
                              void* d_out, int out_size, void* d_ws, size_t ws_size,
                              hipStream_t stream) {
    const float* x    = (const float*)d_in[0];
    const int*   ei   = (const int*)d_in[1];
    const int*   bat  = (const int*)d_in[2];
    const float* W1   = (const float*)d_in[3];
    const float* b1   = (const float*)d_in[4];
    const float* W2   = (const float*)d_in[5];
    const float* b2   = (const float*)d_in[6];
    const float* Wlin = (const float*)d_in[7];
    const float* blin = (const float*)d_in[8];
    float* out = (float*)d_out;

    const int* src = ei;
    const int* dst = ei + NE;

    char* ws = (char*)d_ws;
    size_t off = 0;
    auto alloc = [&](size_t bytes) {
        char* p = ws + off;
        off += (bytes + 255) & ~(size_t)255;
        return p;
    };
    const int NCNT = NBUK * NB;                       // 200192
    int*   counts  = (int*)  alloc(NCNT * sizeof(int));
    int*   offs    = (int*)  alloc(NCNT * sizeof(int));
    int*   bsum    = (int*)  alloc(1024 * sizeof(int));
    int*   row_ptr = (int*)  alloc((NN + 1) * sizeof(int));
    float* dinv    = (float*)alloc(NN * sizeof(float));
    int*   csr_src = (int*)  alloc((size_t)NE * sizeof(int));
    float4* xs     = (float4*)alloc((size_t)NN * sizeof(float4));
    float4* a1     = (float4*)alloc((size_t)NN * sizeof(float4));
    __half* h1     = (__half*)alloc((size_t)NN * HD * sizeof(__half));
    float* a2      = (float*)alloc((size_t)NN * HD * sizeof(float));
    float* pool    = (float*)alloc((size_t)NG * HD * sizeof(float));
    // staging aliases a2 (a2 written only after csr build consumed staging)
    unsigned int* staging = (unsigned int*)a2;
    (void)ws_size; (void)n_in; (void)in_sizes; (void)out_size;

    const int BLK = 256;
    const int nScanBlocks = (NCNT + SBLK - 1) / SBLK;   // 782
    const int gW  = (NN * 64 + BLK - 1) / BLK;          // one wave per node

    // CSR build (no global atomics, block-exclusive write regions)
    hist_k<<<NB, BLK, 0, stream>>>(dst, counts);
    scan1_k<<<nScanBlocks, SBLK, 0, stream>>>(counts, bsum, NCNT);
    scan2_k<<<1, 1024, 0, stream>>>(bsum, nScanBlocks);
    scan3_k<<<nScanBlocks, SBLK, 0, stream>>>(counts, bsum, offs, NCNT);
    stage_k<<<NB, BLK, 0, stream>>>(src, dst, offs, staging);
    csr_fill_bucket_k<<<NBUK, 512, 0, stream>>>(staging, offs, (const float4*)x,
                                                csr_src, row_ptr, dinv, xs);

    // layer 1: aggregate raw x (16 lanes/node) then tiny GEMM -> fp16 h1
    gather1_k<<<(NN * 16 + BLK - 1) / BLK, BLK, 0, stream>>>(xs, csr_src, row_ptr, dinv, a1);
    g1mm_k<<<(NN * 32 + BLK - 1) / BLK, BLK, 0, stream>>>(a1, W1, b1, dinv, (__half2*)h1);

    // layer 2: fp16 gather then GEMM+relu+pool
    gather2_k<<<gW, BLK, 0, stream>>>(h1, csr_src, row_ptr, a2);
    hipMemsetAsync(pool, 0, (size_t)NG * HD * sizeof(float), stream);
    combine2_pool_k<<<NN / 16, BLK, 0, stream>>>(a2, W2, b2, dinv, bat, pool);

    // readout
    final_k<<<NG, 64, 0, stream>>>(pool, bat, Wlin, blin, out);
}

// Round 7
// 254.097 us; speedup vs baseline: 2.0636x; 1.0158x over previous
//
#include <hip/hip_runtime.h>
#include <hip/hip_fp16.h>

#define NN 100000
#define NE 3200000
#define NG 2048
#define FIN 4
#define HD 64
#define BUKSZ 256         // nodes per bucket
#define NBUK 391          // ceil(NN / BUKSZ)
#define NB 512            // stage blocks
#define CHUNK 6250        // NE / NB exactly

// ---------------- pass 1: block-local counting sort by bucket ----------------
// Each block sorts its 6250 edges by bucket (dst>>8) in LDS, writes them
// CONTIGUOUSLY (coalesced, full lines) to staging[b*CHUNK ...], plus
// seg[b*NBUK+k] = local exclusive offset of bucket k, and atomically
// accumulates global per-bucket totals.
// packed value: (dst & 255) << 17 | src   (src < 2^17)

__global__ __launch_bounds__(512) void stage2_k(
        const int* __restrict__ src, const int* __restrict__ dst,
        unsigned int* __restrict__ staging, int* __restrict__ seg,
        int* __restrict__ bucket_tot) {
    __shared__ int hist[NBUK];
    __shared__ int cur[NBUK];
    __shared__ int sc[512];
    __shared__ unsigned int svals[CHUNK];
    int b = blockIdx.x, t = threadIdx.x;
    int base = b * CHUNK;
    for (int i = t; i < NBUK; i += 512) hist[i] = 0;
    __syncthreads();
    for (int i = t; i < CHUNK; i += 512)
        atomicAdd(&hist[dst[base + i] >> 8], 1);
    __syncthreads();
    // exclusive scan of hist[0..390] via 512-wide Hillis-Steele
    int v = (t < NBUK) ? hist[t] : 0;
    sc[t] = v;
    __syncthreads();
    for (int o = 1; o < 512; o <<= 1) {
        int u = (t >= o) ? sc[t - o] : 0;
        __syncthreads();
        sc[t] += u;
        __syncthreads();
    }
    if (t < NBUK) {
        int excl = sc[t] - v;
        seg[b * NBUK + t] = excl;
        cur[t] = excl;
        if (v > 0) atomicAdd(&bucket_tot[t], v);
    }
    __syncthreads();
    // scatter into LDS sorted order
    for (int i = t; i < CHUNK; i += 512) {
        int d = dst[base + i];
        int s = src[base + i];
        int pos = atomicAdd(&cur[d >> 8], 1);
        svals[pos] = ((unsigned int)(d & 255) << 17) | (unsigned int)s;
    }
    __syncthreads();
    // coalesced copy out
    for (int i = t; i < CHUNK; i += 512)
        staging[base + i] = svals[i];
}

// single block: exclusive scan of 391 bucket totals -> bucket_base
__global__ void scanB_k(const int* __restrict__ tot, int* __restrict__ bucket_base) {
    __shared__ int s[512];
    int t = threadIdx.x;
    int v = (t < NBUK) ? tot[t] : 0;
    s[t] = v;
    __syncthreads();
    for (int o = 1; o < 512; o <<= 1) {
        int u = (t >= o) ? s[t - o] : 0;
        __syncthreads();
        s[t] += u;
        __syncthreads();
    }
    if (t < NBUK) bucket_base[t] = s[t] - v;
    if (t == NBUK - 1) bucket_base[NBUK] = s[t];
}

// ---------------- pass 2: per-bucket fine sort -> CSR, row_ptr, dinv, xs ----------------
// block = bucket k; thread t walks stage-block t's segment for this bucket

__global__ __launch_bounds__(512) void csr_fill2_k(
        const unsigned int* __restrict__ staging, const int* __restrict__ seg,
        const int* __restrict__ bucket_base, const float4* __restrict__ x,
        int* __restrict__ csr_src, int* __restrict__ row_ptr,
        float* __restrict__ dinv, float4* __restrict__ xs) {
    __shared__ int degl[BUKSZ];
    __shared__ int sc[BUKSZ];
    __shared__ int cur[BUKSZ];
    int k = blockIdx.x;
    int t = threadIdx.x;
    int nodeBase = k * BUKSZ;
    int s0 = bucket_base[k];
    if (t < BUKSZ) degl[t] = 0;
    __syncthreads();
    int segBeg = seg[t * NBUK + k];
    int segEnd = (k < NBUK - 1) ? seg[t * NBUK + k + 1] : CHUNK;
    int cbase = t * CHUNK;
    for (int i = segBeg; i < segEnd; ++i)
        atomicAdd(&degl[staging[cbase + i] >> 17], 1);
    __syncthreads();
    int v = 0;
    if (t < BUKSZ) { v = degl[t]; sc[t] = v; }
    __syncthreads();
    for (int o = 1; o < BUKSZ; o <<= 1) {
        int u = 0;
        if (t < BUKSZ && t >= o) u = sc[t - o];
        __syncthreads();
        if (t < BUKSZ && t >= o) sc[t] += u;
        __syncthreads();
    }
    if (t < BUKSZ) {
        int excl = sc[t] - v;
        int node = nodeBase + t;
        if (node < NN) {
            row_ptr[node] = s0 + excl;
            float di = rsqrtf((float)v + 1.0f);
            dinv[node] = di;
            float4 xv = x[node];
            xs[node] = make_float4(xv.x * di, xv.y * di, xv.z * di, xv.w * di);
        }
        cur[t] = s0 + excl;
        if (k == NBUK - 1 && t == 0) row_ptr[NN] = NE;
    }
    __syncthreads();
    for (int i = segBeg; i < segEnd; ++i) {
        unsigned int pv = staging[cbase + i];
        int pos = atomicAdd(&cur[pv >> 17], 1);
        csr_src[pos] = (int)(pv & 0x1FFFFu);
    }
}

// ---------------- layer 1: aggregate raw 4-feature x, 16 lanes per node ----------------

__global__ void gather1_k(const float4* __restrict__ xs, const int* __restrict__ csr_src,
                          const int* __restrict__ row_ptr, const float* __restrict__ dinv,
                          float4* __restrict__ a1) {
    int tid = blockIdx.x * blockDim.x + threadIdx.x;
    int node = tid >> 4;
    int sub = tid & 15;
    if (node >= NN) return;
    int beg = row_ptr[node], end = row_ptr[node + 1];
    float4 s = make_float4(0.f, 0.f, 0.f, 0.f);
    for (int e = beg + sub; e < end; e += 16) {
        float4 w = xs[csr_src[e]];
        s.x += w.x; s.y += w.y; s.z += w.z; s.w += w.w;
    }
#pragma unroll
    for (int o = 1; o < 16; o <<= 1) {
        s.x += __shfl_xor(s.x, o);
        s.y += __shfl_xor(s.y, o);
        s.z += __shfl_xor(s.z, o);
        s.w += __shfl_xor(s.w, o);
    }
    if (sub == 0) {
        float4 self = xs[node];
        float di = dinv[node];
        a1[node] = make_float4((s.x + self.x) * di, (s.y + self.y) * di,
                               (s.z + self.z) * di, (s.w + self.w) * di);
    }
}

// h1[node][2j..2j+1] = fp16( dinv[node] * relu(a1 @ W1 + b1) )
__global__ void g1mm_k(const float4* __restrict__ a1, const float* __restrict__ W1,
                       const float* __restrict__ b1, const float* __restrict__ dinv,
                       __half2* __restrict__ h1) {
    int t = blockIdx.x * blockDim.x + threadIdx.x;
    if (t >= NN * 32) return;
    int node = t >> 5, j = (t & 31) << 1;
    float4 a = a1[node];
    float di = dinv[node];
    float v0 = a.x * W1[j] + a.y * W1[64 + j] + a.z * W1[128 + j] + a.w * W1[192 + j] + b1[j];
    float v1 = a.x * W1[j + 1] + a.y * W1[64 + j + 1] + a.z * W1[128 + j + 1] + a.w * W1[192 + j + 1] + b1[j + 1];
    v0 = fmaxf(v0, 0.f) * di;
    v1 = fmaxf(v1, 0.f) * di;
    h1[t] = __floats2half2_rn(v0, v1);
}

// ---------------- layer 2 gather: wave = 1 dst node, 8 edges/half-wave/iter ----------------

__global__ void gather2_k(const __half* __restrict__ h1, const int* __restrict__ csr_src,
                          const int* __restrict__ row_ptr, float* __restrict__ a2) {
    int wid = (blockIdx.x * blockDim.x + threadIdx.x) >> 6;
    int lane = threadIdx.x & 63;
    if (wid >= NN) return;
    int half = lane >> 5, f2 = lane & 31;
    int beg = row_ptr[wid], end = row_ptr[wid + 1];
    float ax = 0.f, ay = 0.f;
    int e = beg + half;
    for (; e + 14 < end; e += 16) {        // 8 edges per half per iter
        int s0 = csr_src[e],      s1 = csr_src[e + 2];
        int s2 = csr_src[e + 4],  s3 = csr_src[e + 6];
        int s4 = csr_src[e + 8],  s5 = csr_src[e + 10];
        int s6 = csr_src[e + 12], s7 = csr_src[e + 14];
        float2 f0 = __half22float2(((const __half2*)(h1 + (size_t)s0 * HD))[f2]);
        float2 f1 = __half22float2(((const __half2*)(h1 + (size_t)s1 * HD))[f2]);
        float2 f3 = __half22float2(((const __half2*)(h1 + (size_t)s2 * HD))[f2]);
        float2 f4 = __half22float2(((const __half2*)(h1 + (size_t)s3 * HD))[f2]);
        float2 f5 = __half22float2(((const __half2*)(h1 + (size_t)s4 * HD))[f2]);
        float2 f6 = __half22float2(((const __half2*)(h1 + (size_t)s5 * HD))[f2]);
        float2 f7 = __half22float2(((const __half2*)(h1 + (size_t)s6 * HD))[f2]);
        float2 f8 = __half22float2(((const __half2*)(h1 + (size_t)s7 * HD))[f2]);
        ax += ((f0.x + f1.x) + (f3.x + f4.x)) + ((f5.x + f6.x) + (f7.x + f8.x));
        ay += ((f0.y + f1.y) + (f3.y + f4.y)) + ((f5.y + f6.y) + (f7.y + f8.y));
    }
    for (; e + 2 < end; e += 4) {          // 2 edges
        int s0 = csr_src[e], s1 = csr_src[e + 2];
        float2 f0 = __half22float2(((const __half2*)(h1 + (size_t)s0 * HD))[f2]);
        float2 f1 = __half22float2(((const __half2*)(h1 + (size_t)s1 * HD))[f2]);
        ax += f0.x + f1.x;
        ay += f0.y + f1.y;
    }
    for (; e < end; e += 2) {
        int s0 = csr_src[e];
        float2 f0 = __half22float2(((const __half2*)(h1 + (size_t)s0 * HD))[f2]);
        ax += f0.x; ay += f0.y;
    }
    ax += __shfl_xor(ax, 32);
    ay += __shfl_xor(ay, 32);
    float2 self = __half22float2(((const __half2*)(h1 + (size_t)wid * HD))[f2]);
    ax += self.x; ay += self.y;
    if (half == 0)
        ((float2*)(a2 + (size_t)wid * HD))[f2] = make_float2(ax, ay);
}

// ---------------- combine2 + pool ----------------

__global__ void combine2_pool_k(const float* __restrict__ a2, const float* __restrict__ W2,
                                const float* __restrict__ b2, const float* __restrict__ dinv,
                                const int* __restrict__ batch, float* __restrict__ pool) {
    __shared__ float w2s[HD * HD];
    __shared__ float as2[16][HD];
    __shared__ float vals[16][HD];
    __shared__ int   bt[16];
    int tid = threadIdx.x;
    int wave = tid >> 6, lane = tid & 63;
    int base = blockIdx.x * 16;
    for (int i = tid; i < HD * HD; i += 256) w2s[i] = W2[i];
    for (int i = tid; i < 16 * HD; i += 256) as2[i >> 6][i & 63] = a2[(size_t)base * HD + i];
    if (tid < 16) bt[tid] = batch[base + tid];
    __syncthreads();
#pragma unroll
    for (int i = 0; i < 4; ++i) {
        int nl = wave * 4 + i;
        float s = 0.f;
#pragma unroll
        for (int k = 0; k < HD; ++k) s = fmaf(as2[nl][k], w2s[k * HD + lane], s);
        float v = fmaxf(fmaf(dinv[base + nl], s, b2[lane]), 0.f);
        vals[nl][lane] = v;
    }
    __syncthreads();
    if (wave == 0) {
        int g = bt[0];
        float acc = 0.f;
        for (int i = 0; i < 16; ++i) {
            int bg = bt[i];
            if (bg != g) { atomicAdd(&pool[g * HD + lane], acc); acc = 0.f; g = bg; }
            acc += vals[i][lane];
        }
        atomicAdd(&pool[g * HD + lane], acc);
    }
}

__device__ __forceinline__ int lb_dev(const int* __restrict__ b, int n, int key) {
    int lo = 0, hi = n;
    while (lo < hi) {
        int mid = (lo + hi) >> 1;
        if (b[mid] < key) lo = mid + 1; else hi = mid;
    }
    return lo;
}

__global__ void final_k(const float* __restrict__ pool, const int* __restrict__ batch,
                        const float* __restrict__ Wlin, const float* __restrict__ blin,
                        float* __restrict__ out) {
    int g = blockIdx.x;
    int lane = threadIdx.x;
    int lo = lb_dev(batch, NN, g);
    int hi = lb_dev(batch, NN, g + 1);
    float cnt = (float)(hi - lo);
    float v = pool[g * HD + lane] * Wlin[lane];
#pragma unroll
    for (int off = 32; off > 0; off >>= 1) v += __shfl_down(v, off);
    if (lane == 0) out[g] = v / fmaxf(cnt, 1.0f) + blin[0];
}

// ---------------- launch ----------------

extern "C" void kernel_launch(void* const* d_in, const int* in_sizes, int n_in,
                              void* d_out, int out_size, void* d_ws, size_t ws_size,
                              hipStream_t stream) {
    const float* x    = (const float*)d_in[0];
    const int*   ei   = (const int*)d_in[1];
    const int*   bat  = (const int*)d_in[2];
    const float* W1   = (const float*)d_in[3];
    const float* b1   = (const float*)d_in[4];
    const float* W2   = (const float*)d_in[5];
    const float* b2   = (const float*)d_in[6];
    const float* Wlin = (const float*)d_in[7];
    const float* blin = (const float*)d_in[8];
    float* out = (float*)d_out;

    const int* src = ei;
    const int* dst = ei + NE;

    char* ws = (char*)d_ws;
    size_t off = 0;
    auto alloc = [&](size_t bytes) {
        char* p = ws + off;
        off += (bytes + 255) & ~(size_t)255;
        return p;
    };
    int*   seg      = (int*)  alloc((size_t)NB * NBUK * sizeof(int));   // 800 KB
    int*   btot     = (int*)  alloc((NBUK + 1) * sizeof(int));
    int*   bbase    = (int*)  alloc((NBUK + 1) * sizeof(int));
    int*   row_ptr  = (int*)  alloc((NN + 1) * sizeof(int));
    float* dinv     = (float*)alloc(NN * sizeof(float));
    int*   csr_src  = (int*)  alloc((size_t)NE * sizeof(int));
    float4* xs      = (float4*)alloc((size_t)NN * sizeof(float4));
    float4* a1      = (float4*)alloc((size_t)NN * sizeof(float4));
    __half* h1      = (__half*)alloc((size_t)NN * HD * sizeof(__half));
    float* a2       = (float*)alloc((size_t)NN * HD * sizeof(float));
    float* pool     = (float*)alloc((size_t)NG * HD * sizeof(float));
    // staging aliases a2 (consumed by csr build before a2 is written)
    unsigned int* staging = (unsigned int*)a2;
    (void)ws_size; (void)n_in; (void)in_sizes; (void)out_size;

    const int BLK = 256;
    const int gW  = (NN * 64 + BLK - 1) / BLK;          // one wave per node

    // CSR build
    hipMemsetAsync(btot, 0, (NBUK + 1) * sizeof(int), stream);
    stage2_k<<<NB, 512, 0, stream>>>(src, dst, staging, seg, btot);
    scanB_k<<<1, 512, 0, stream>>>(btot, bbase);
    csr_fill2_k<<<NBUK, 512, 0, stream>>>(staging, seg, bbase, (const float4*)x,
                                          csr_src, row_ptr, dinv, xs);

    // layer 1: aggregate raw x (16 lanes/node) then tiny GEMM -> fp16 h1
    gather1_k<<<(NN * 16 + BLK - 1) / BLK, BLK, 0, stream>>>(xs, csr_src, row_ptr, dinv, a1);
    g1mm_k<<<(NN * 32 + BLK - 1) / BLK, BLK, 0, stream>>>(a1, W1, b1, dinv, (__half2*)h1);

    // layer 2: fp16 gather then GEMM+relu+pool
    gather2_k<<<gW, BLK, 0, stream>>>(h1, csr_src, row_ptr, a2);
    hipMemsetAsync(pool, 0, (size_t)NG * HD * sizeof(float), stream);
    combine2_pool_k<<<NN / 16, BLK, 0, stream>>>(a2, W2, b2, dinv, bat, pool);

    // readout
    final_k<<<NG, 64, 0, stream>>>(pool, bat, Wlin, blin, out);
}